// Round 4
// baseline (697.038 us; speedup 1.0000x reference)
//
#include <hip/hip_runtime.h>
#include <hip/hip_bf16.h>

typedef __attribute__((ext_vector_type(8))) short short8;
typedef __attribute__((ext_vector_type(4))) float f32x4;
typedef const __attribute__((address_space(1))) void GVOID;
typedef __attribute__((address_space(3))) void LVOID;

#define DI __device__ __forceinline__

DI unsigned short f2b(float f){
  union{float ff; unsigned u;} v; v.ff=f;
  unsigned r = v.u;
  r += 0x7fffu + ((r>>16)&1u);   // RNE
  return (unsigned short)(r>>16);
}
DI float b2f(unsigned short h){
  union{unsigned u; float ff;} v; v.u = ((unsigned)h)<<16; return v.ff;
}

DI void glds16(const void* g, void* l){
  __builtin_amdgcn_global_load_lds((GVOID*)g, (LVOID*)l, 16, 0, 0);
}

DI float dot8(short8 wv, const float* x){
  float s = 0.f;
  #pragma unroll
  for (int i=0;i<8;++i) s += b2f((unsigned short)wv[i]) * x[i];
  return s;
}

// block-wide (256 thr) sum of two values
DI void bred2(float& a, float& b, float* red){
  #pragma unroll
  for (int o=32;o>0;o>>=1){ a += __shfl_xor(a,o); b += __shfl_xor(b,o); }
  int wid = threadIdx.x>>6;
  __syncthreads();
  if ((threadIdx.x&63)==0){ red[wid*2]=a; red[wid*2+1]=b; }
  __syncthreads();
  a = red[0]+red[2]+red[4]+red[6];
  b = red[1]+red[3]+red[5]+red[7];
}

// ---------------- k0: prep ----------------
// blocks 0..511   : Wg = g-scaled [Wk;Wv] bf16 rows + c1/c0 reduction
// blocks 512..1087: flat bf16 copies of Wih,Whh,W1,W2,Wq
// blocks 1088..1343: slot init + q0
// blocks 1344..3391: per-row LN stats of embeddings (m, inv) -> rstats
__global__ void k0(const float* __restrict__ Wk, const float* __restrict__ Wv,
                   const float* __restrict__ Wih, const float* __restrict__ Whh,
                   const float* __restrict__ W1, const float* __restrict__ W2,
                   const float* __restrict__ Wq,
                   const float* __restrict__ lnig, const float* __restrict__ lnib,
                   unsigned short* Wgb, unsigned short* Wihb, unsigned short* Whhb,
                   unsigned short* W1b, unsigned short* W2b, unsigned short* Wqb,
                   float* c1c0,
                   const float* __restrict__ noise, const float* __restrict__ mu,
                   const float* __restrict__ ls, const float* __restrict__ lnsg,
                   const float* __restrict__ lnsb,
                   float* slots, unsigned short* qbuf,
                   const float* __restrict__ emb, float2* rstats){
  __shared__ __align__(16) float sn[256];
  __shared__ float red[8];
  int t = threadIdx.x, blk = blockIdx.x;
  if (blk < 512){
    int dout = blk;
    const float* src = (dout < 256) ? (Wk + dout*256) : (Wv + (dout-256)*256);
    float wv = src[t];
    float g = lnig[t], bb = lnib[t];
    float wg = wv*g;
    Wgb[dout*256 + t] = f2b(wg);
    float c1 = wg, c0 = wv*bb;
    bred2(c1, c0, red);
    if (t == 0){ c1c0[dout] = c1; c1c0[512 + dout] = c0; }
  } else if (blk < 1088){
    int j = (blk-512)*1024 + t*4;
    const float* sp; unsigned short* dp;
    if (j < 196608){ sp=Wih+j; dp=Wihb+j; }
    else if (j < 393216){ sp=Whh+(j-196608); dp=Whhb+(j-196608); }
    else if (j < 458752){ sp=W1+(j-393216); dp=W1b+(j-393216); }
    else if (j < 524288){ sp=W2+(j-458752); dp=W2b+(j-458752); }
    else { sp=Wq+(j-524288); dp=Wqb+(j-524288); }
    float4 v = *(const float4*)sp;
    dp[0]=f2b(v.x); dp[1]=f2b(v.y); dp[2]=f2b(v.z); dp[3]=f2b(v.w);
  } else if (blk < 1344){
    int r = blk - 1088;
    int b = r>>3, k = r&7;
    float val = mu[t] + __expf(ls[t]) * noise[r*256 + t];
    slots[r*256 + t] = val;
    qbuf[(b*16 + 8 + k)*256 + t] = 0;      // zero q pad rows (slots 8..15)
    float sa = val, sb = val*val;
    bred2(sa, sb, red);
    float m = sa*(1.f/256.f);
    float var = sb*(1.f/256.f) - m*m;
    float inv = rsqrtf(fmaxf(var, 0.f) + 1e-5f);
    sn[t] = (val - m)*inv*lnsg[t] + lnsb[t];
    __syncthreads();
    const float* wr = Wq + (size_t)t*256;
    float acc = 0.f;
    #pragma unroll 8
    for (int c=0;c<64;++c){
      float4 wv = *(const float4*)(wr + c*4);
      acc += wv.x*sn[c*4] + wv.y*sn[c*4+1] + wv.z*sn[c*4+2] + wv.w*sn[c*4+3];
    }
    qbuf[(b*16 + k)*256 + t] = f2b(acc * 0.0625f);   // SCALE folded in
  } else {
    // LN row stats: each wave handles 16 rows, whole-wave contiguous 1KB row reads
    int w = t>>6, l = t&63;
    int rbase = (blk-1344)*64 + w*16;
    #pragma unroll
    for (int p=0;p<2;++p){
      float s[8], q[8];
      #pragma unroll
      for (int j=0;j<8;++j){
        int row = rbase + p*8 + j;
        float4 v = *(const float4*)(emb + (size_t)row*256 + l*4);
        s[j] = v.x+v.y+v.z+v.w;
        q[j] = v.x*v.x + v.y*v.y + v.z*v.z + v.w*v.w;
      }
      #pragma unroll
      for (int off=1; off<64; off<<=1){
        #pragma unroll
        for (int j=0;j<8;++j){ s[j] += __shfl_xor(s[j],off); q[j] += __shfl_xor(q[j],off); }
      }
      if (l == 0){
        #pragma unroll
        for (int j=0;j<8;++j){
          int row = rbase + p*8 + j;
          float m = s[j]*(1.f/256.f);
          float var = q[j]*(1.f/256.f) - m*m;
          float inv = rsqrtf(fmaxf(var,0.f) + 1e-5f);
          rstats[row] = make_float2(m, inv);
        }
      }
    }
  }
}

// ---------------- k1b: keys/values projection with LN folded ----------------
// grid 4096 = 32 b x 128 strips of 32 n; 256 thr (4 waves).
// Stage raw emb f32 tile (32KB) linear via global_load_lds; extract bf16 A-frags once;
// per chunk: wave w computes its 16-dout column over both row-tiles.
// keys stored [b][n][chunk^ (n&7)] bf16; values as panels vpan[b][strip][dout][32n] with chunk^(dout&3).
__global__ __launch_bounds__(256) void k1b(const float* __restrict__ emb,
                                           const unsigned short* __restrict__ Wgb,
                                           const float2* __restrict__ rstats,
                                           const float* __restrict__ c1c0,
                                           unsigned short* __restrict__ keys,
                                           unsigned short* __restrict__ vpan){
  __shared__ __align__(16) char xl[32768];   // f32 tile [32][256]; reused as epilogue scratch
  int t = threadIdx.x, blk = blockIdx.x;
  int w = t>>6, l = t&63, l15 = l&15, lg = (l>>4)&3;
  int b = blk>>7, strip = blk&127;
  int n0 = strip*32;
  const char* ebase = (const char*)(emb + ((size_t)b*4096 + n0)*256);
  {
    char* dst = xl + w*8192;
    const char* src = ebase + w*8192;
    #pragma unroll
    for (int i=0;i<8;++i) glds16(src + i*1024 + l*16, dst + i*1024 + l*16);
  }
  // row stats for this lane's C-frag rows (hoisted)
  float m0[4], i0[4], m1[4], i1[4];
  #pragma unroll
  for (int q=0;q<4;++q){
    float2 s0 = rstats[(size_t)b*4096 + n0 + lg*4 + q];
    float2 s1 = rstats[(size_t)b*4096 + n0 + 16 + lg*4 + q];
    m0[q]=s0.x; i0[q]=s0.y; m1[q]=s1.x; i1[q]=s1.y;
  }
  asm volatile("s_waitcnt vmcnt(0)" ::: "memory");
  __syncthreads();
  // A-fragments (bf16) into regs, once. row tile0 = l15, tile1 = 16+l15.
  short8 af0[8], af1[8];
  #pragma unroll
  for (int s=0;s<8;++s){
    int off0 = l15*1024 + lg*32 + s*128;
    int off1 = (16+l15)*1024 + lg*32 + s*128;
    f32x4 A0 = *(const f32x4*)(xl + off0);
    f32x4 B0 = *(const f32x4*)(xl + off0 + 16);
    f32x4 A1 = *(const f32x4*)(xl + off1);
    f32x4 B1 = *(const f32x4*)(xl + off1 + 16);
    short8 r0, r1;
    #pragma unroll
    for (int i=0;i<4;++i){ r0[i] = (short)f2b(A0[i]); r0[4+i] = (short)f2b(B0[i]); }
    #pragma unroll
    for (int i=0;i<4;++i){ r1[i] = (short)f2b(A1[i]); r1[4+i] = (short)f2b(B1[i]); }
    af0[s] = r0; af1[s] = r1;
  }
  f32x4 z4 = {0.f,0.f,0.f,0.f};
  unsigned short* st = (unsigned short*)xl;
  #pragma unroll 1
  for (int c=0;c<8;++c){
    int dout = c*64 + w*16 + l15;
    const unsigned short* wp = Wgb + (size_t)dout*256 + lg*8;
    short8 bf[8];
    #pragma unroll
    for (int s=0;s<8;++s) bf[s] = *(const short8*)(wp + s*32);
    f32x4 a00=z4, a01=z4, a10=z4, a11=z4;
    #pragma unroll
    for (int s=0;s<4;++s){
      a00 = __builtin_amdgcn_mfma_f32_16x16x32_bf16(af0[s], bf[s], a00, 0,0,0);
      a10 = __builtin_amdgcn_mfma_f32_16x16x32_bf16(af1[s], bf[s], a10, 0,0,0);
      a01 = __builtin_amdgcn_mfma_f32_16x16x32_bf16(af0[s+4], bf[s+4], a01, 0,0,0);
      a11 = __builtin_amdgcn_mfma_f32_16x16x32_bf16(af1[s+4], bf[s+4], a11, 0,0,0);
    }
    float c1d = c1c0[dout], c0d = c1c0[512 + dout];
    float kv0[4], kv1[4];
    #pragma unroll
    for (int q=0;q<4;++q){
      kv0[q] = i0[q]*(a00[q]+a01[q]) + (c0d - m0[q]*i0[q]*c1d);
      kv1[q] = i1[q]*(a10[q]+a11[q]) + (c0d - m1[q]*i1[q]*c1d);
    }
    __syncthreads();
    if (c < 4){
      // keys: st[32 n][72]
      int co = w*16 + l15;
      #pragma unroll
      for (int q=0;q<4;++q){
        st[(lg*4+q)*72 + co]      = f2b(kv0[q]);
        st[(16+lg*4+q)*72 + co]   = f2b(kv1[q]);
      }
      __syncthreads();
      int row2 = t>>3, seg = t&7;
      int4 dv = *(const int4*)(st + row2*72 + seg*8);
      size_t base = ((size_t)b*4096 + n0 + row2)*256;
      *(int4*)(keys + base + ((c*8 + seg) ^ (row2&7))*8) = dv;
    } else {
      // values: st[64 dout][40]
      int co = w*16 + l15;
      #pragma unroll
      for (int q=0;q<4;++q){
        st[co*40 + lg*4+q]      = f2b(kv0[q]);
        st[co*40 + 16+lg*4+q]   = f2b(kv1[q]);
      }
      __syncthreads();
      int dl = t>>2, ch = t&3;
      int4 dv = *(const int4*)(st + dl*40 + ch*8);
      int dout_g = (c-4)*64 + dl;
      size_t base = (((size_t)b*128 + strip)*256 + dout_g)*32;
      *(int4*)(vpan + base + ((ch ^ (dout_g&3))*8)) = dv;
    }
  }
}

// ---------------- k3: dots -> softmax(K) -> partial S / unnormalized updates ----------------
// grid 4096 = 32 b x 128 strips of 32 n; 256 thr (4 waves).
// Stage K-strip (16KB) + V-panel (16KB) as contiguous streams; 2 barriers.
__global__ __launch_bounds__(256) void k3(const unsigned short* __restrict__ keys,
                                          const unsigned short* __restrict__ vpan,
                                          const unsigned short* __restrict__ qbuf,
                                          float* __restrict__ Upart, float* __restrict__ Spart,
                                          float* __restrict__ outA, int last){
  __shared__ __align__(16) char kl[16384];   // keys [32 n][512B], pre-swizzled
  __shared__ __align__(16) char vl[16384];   // vpan [256 dout][64B], pre-swizzled
  __shared__ __align__(16) char al[1024];    // attn [16 slots][64B], swizzled
  __shared__ float sS[2][8];
  int t = threadIdx.x, w = t>>6, l = t&63;
  int l15 = l&15, lg = (l>>4)&3;
  int b = blockIdx.x >> 7;
  int strip = blockIdx.x & 127;
  int n0 = strip*32;
  {
    const char* ks = (const char*)(keys + ((size_t)b*4096 + n0)*256) + w*4096;
    const char* vs = (const char*)(vpan + (((size_t)b*128 + strip)*256)*32) + w*4096;
    char* kd = kl + w*4096;
    char* vd = vl + w*4096;
    #pragma unroll
    for (int i=0;i<4;++i){
      glds16(ks + i*1024 + l*16, kd + i*1024 + l*16);
      glds16(vs + i*1024 + l*16, vd + i*1024 + l*16);
    }
  }
  if (t < 32){ int4 zz = {0,0,0,0}; ((int4*)(al + 512))[t] = zz; }  // pad slots 8..15 = 0
  asm volatile("s_waitcnt vmcnt(0)" ::: "memory");
  __syncthreads();
  f32x4 z4 = {0.f,0.f,0.f,0.f};
  if (w < 2){
    // dots for n-group w (16 n)
    short8 qf[8], kf[8];
    const unsigned short* qb = qbuf + (size_t)b*4096 + l15*256 + lg*8;
    #pragma unroll
    for (int s=0;s<8;++s) qf[s] = *(const short8*)(qb + s*32);
    int nloc = w*16 + l15;
    #pragma unroll
    for (int s=0;s<8;++s)
      kf[s] = *(const short8*)(kl + nloc*512 + (((lg + s*4) ^ (nloc&7))<<4));
    f32x4 dacc = z4;
    #pragma unroll
    for (int s=0;s<8;++s)
      dacc = __builtin_amdgcn_mfma_f32_16x16x32_bf16(qf[s], kf[s], dacc, 0,0,0);
    // softmax over 8 slots per n (slots 0-3 lanes 0-15, slots 4-7 lanes 16-31)
    float d0=dacc[0], d1=dacc[1], d2=dacc[2], d3=dacc[3];
    float mx = fmaxf(fmaxf(d0,d1), fmaxf(d2,d3));
    mx = fmaxf(mx, __shfl_xor(mx,16));
    float e0=__expf(d0-mx), e1=__expf(d1-mx), e2=__expf(d2-mx), e3=__expf(d3-mx);
    float se = e0+e1+e2+e3;
    se += __shfl_xor(se,16);
    float inv = 1.f/se;
    float a0=e0*inv+1e-8f, a1=e1*inv+1e-8f, a2=e2*inv+1e-8f, a3=e3*inv+1e-8f;
    float sp[4] = {a0,a1,a2,a3};
    if (l < 32){
      int rr = lg<<2;
      #pragma unroll
      for (int j=0;j<4;++j){
        float av = (j==0)?a0:((j==1)?a1:((j==2)?a2:a3));
        int slot = rr + j;
        *(unsigned short*)(al + slot*64 + (((nloc>>3) ^ (slot&3))<<4) + (nloc&7)*2) = f2b(av);
      }
      if (last){
        size_t o = ((size_t)b*8 + rr)*4096 + n0 + nloc;
        outA[o] = a0; outA[o+4096]=a1; outA[o+8192]=a2; outA[o+12288]=a3;
      }
      #pragma unroll
      for (int j=0;j<4;++j){
        sp[j] += __shfl_xor(sp[j],1);
        sp[j] += __shfl_xor(sp[j],2);
        sp[j] += __shfl_xor(sp[j],4);
        sp[j] += __shfl_xor(sp[j],8);
      }
      if (l15 == 0){
        int rr2 = lg<<2;
        sS[w][rr2+0]=sp[0]; sS[w][rr2+1]=sp[1]; sS[w][rr2+2]=sp[2]; sS[w][rr2+3]=sp[3];
      }
    }
  }
  __syncthreads();
  if (t < 8) Spart[(size_t)blockIdx.x*8 + t] = sS[0][t] + sS[1][t];
  // PV: wave w owns douts 64w..64w+63 (4 MFMA)
  short8 afr = *(const short8*)(al + l15*64 + ((lg ^ (l15&3))<<4));
  f32x4 upd[4];
  #pragma unroll
  for (int dt=0;dt<4;++dt){
    int dout = 64*w + 16*dt + l15;
    short8 bfv = *(const short8*)(vl + dout*64 + ((lg ^ (dout&3))<<4));
    upd[dt] = __builtin_amdgcn_mfma_f32_16x16x32_bf16(afr, bfv, z4, 0,0,0);
  }
  if (l < 32){
    int rr = lg<<2;
    float* up = Upart + (size_t)blockIdx.x*2048;
    #pragma unroll
    for (int dt=0;dt<4;++dt){
      int dout = 64*w + 16*dt + l15;
      up[(rr+0)*256 + dout] = upd[dt][0];
      up[(rr+1)*256 + dout] = upd[dt][1];
      up[(rr+2)*256 + dout] = upd[dt][2];
      up[(rr+3)*256 + dout] = upd[dt][3];
    }
  }
}

// ---------------- k4: partial-reduce + GRU + residual MLP + next queries ----------------
__global__ void k4(const float* __restrict__ Upart, const float* __restrict__ Spart,
                   float* __restrict__ slots,
                   const float* __restrict__ bih, const float* __restrict__ bhh,
                   const unsigned short* __restrict__ Wihb, const unsigned short* __restrict__ Whhb,
                   const unsigned short* __restrict__ W1b, const unsigned short* __restrict__ W2b,
                   const unsigned short* __restrict__ Wqb,
                   const float* __restrict__ pb1, const float* __restrict__ pb2,
                   const float* __restrict__ lnfg, const float* __restrict__ lnfb,
                   const float* __restrict__ lnsg, const float* __restrict__ lnsb,
                   unsigned short* __restrict__ qbuf, float* __restrict__ outS, int last){
  __shared__ __align__(16) float uh[512];
  __shared__ __align__(16) float yl[256];
  __shared__ __align__(16) float y1l[256];
  __shared__ float red[8];
  int r = blockIdx.x, t = threadIdx.x;
  int b = r>>3, k = r&7;
  float Sr = 0.f, u = 0.f;
  #pragma unroll 8
  for (int nb=0;nb<128;++nb){
    size_t bn = (size_t)(b*128 + nb);
    Sr += Spart[bn*8 + k];
    u  += Upart[bn*2048 + k*256 + t];
  }
  u /= Sr;
  float h = slots[r*256 + t];
  uh[t] = u; uh[256 + t] = h;
  __syncthreads();
  float gir = bih[t], giz = bih[256+t], gin = bih[512+t];
  float ghr = bhh[t], ghz = bhh[256+t], ghn = bhh[512+t];
  {
    const unsigned short* p0 = Wihb + (size_t)t*256;
    const unsigned short* p1 = Wihb + (size_t)(256+t)*256;
    const unsigned short* p2 = Wihb + (size_t)(512+t)*256;
    const unsigned short* p3 = Whhb + (size_t)t*256;
    const unsigned short* p4 = Whhb + (size_t)(256+t)*256;
    const unsigned short* p5 = Whhb + (size_t)(512+t)*256;
    #pragma unroll 2
    for (int c=0;c<32;++c){
      const float* ux = uh + c*8;
      const float* hx = uh + 256 + c*8;
      gir += dot8(*(const short8*)(p0 + c*8), ux);
      giz += dot8(*(const short8*)(p1 + c*8), ux);
      gin += dot8(*(const short8*)(p2 + c*8), ux);
      ghr += dot8(*(const short8*)(p3 + c*8), hx);
      ghz += dot8(*(const short8*)(p4 + c*8), hx);
      ghn += dot8(*(const short8*)(p5 + c*8), hx);
    }
  }
  float rg = 1.f/(1.f+__expf(-(gir+ghr)));
  float zz = 1.f/(1.f+__expf(-(giz+ghz)));
  float ng = tanhf(gin + rg*ghn);
  float s1 = (1.f-zz)*ng + zz*h;
  float sa = s1, sb = s1*s1;
  bred2(sa, sb, red);
  float m = sa*(1.f/256.f);
  float var = sb*(1.f/256.f) - m*m;
  float yv = (s1-m)*rsqrtf(fmaxf(var,0.f)+1e-5f)*lnfg[t] + lnfb[t];
  yl[t] = yv;
  __syncthreads();
  float a1 = pb1[t];
  const unsigned short* q1 = W1b + (size_t)t*256;
  #pragma unroll 2
  for (int c=0;c<32;++c) a1 += dot8(*(const short8*)(q1 + c*8), yl + c*8);
  float y1 = (a1 > 0.f) ? a1 : 0.01f*a1;
  y1l[t] = y1;
  __syncthreads();
  float a2 = pb2[t];
  const unsigned short* q2 = W2b + (size_t)t*256;
  #pragma unroll 2
  for (int c=0;c<32;++c) a2 += dot8(*(const short8*)(q2 + c*8), y1l + c*8);
  float s2v = s1 + a2;
  slots[r*256 + t] = s2v;
  if (last){
    outS[r*256 + t] = s2v;
  } else {
    float ta = s2v, tb = s2v*s2v;
    bred2(ta, tb, red);
    float m2 = ta*(1.f/256.f);
    float v2 = tb*(1.f/256.f) - m2*m2;
    float snv = (s2v - m2)*rsqrtf(fmaxf(v2,0.f)+1e-5f)*lnsg[t] + lnsb[t];
    __syncthreads();
    yl[t] = snv;
    __syncthreads();
    float aq = 0.f;
    const unsigned short* q3 = Wqb + (size_t)t*256;
    #pragma unroll 2
    for (int c=0;c<32;++c) aq += dot8(*(const short8*)(q3 + c*8), yl + c*8);
    qbuf[(b*16 + k)*256 + t] = f2b(aq * 0.0625f);
  }
}

extern "C" void kernel_launch(void* const* d_in, const int* in_sizes, int n_in,
                              void* d_out, int out_size, void* d_ws, size_t ws_size,
                              hipStream_t stream) {
  (void)in_sizes; (void)n_in; (void)out_size; (void)ws_size;
  const float* emb  = (const float*)d_in[0];
  const float* noise= (const float*)d_in[1];
  const float* mu   = (const float*)d_in[2];
  const float* ls   = (const float*)d_in[3];
  const float* Wq   = (const float*)d_in[4];
  const float* Wk   = (const float*)d_in[5];
  const float* Wv   = (const float*)d_in[6];
  const float* Wih  = (const float*)d_in[7];
  const float* Whh  = (const float*)d_in[8];
  const float* bih  = (const float*)d_in[9];
  const float* bhh  = (const float*)d_in[10];
  const float* W1   = (const float*)d_in[11];
  const float* b1   = (const float*)d_in[12];
  const float* W2   = (const float*)d_in[13];
  const float* b2   = (const float*)d_in[14];
  const float* lnig = (const float*)d_in[15];
  const float* lnib = (const float*)d_in[16];
  const float* lnsg = (const float*)d_in[17];
  const float* lnsb = (const float*)d_in[18];
  const float* lnfg = (const float*)d_in[19];
  const float* lnfb = (const float*)d_in[20];

  unsigned short* keys = (unsigned short*)d_ws;      // 33,554,432
  unsigned short* vpan = keys + 33554432;            // 33,554,432
  unsigned short* Wgb  = vpan + 33554432;            // 131,072
  unsigned short* Wihb = Wgb + 131072;               // 196,608
  unsigned short* Whhb = Wihb + 196608;              // 196,608
  unsigned short* W1b  = Whhb + 196608;              // 65,536
  unsigned short* W2b  = W1b + 65536;                // 65,536
  unsigned short* Wqb  = W2b + 65536;                // 65,536
  unsigned short* qbuf = Wqb + 65536;                // 131,072
  float* slots = (float*)(qbuf + 131072);            // 65,536 f32
  float2* rstats = (float2*)(slots + 65536);         // 131,072 float2
  float* c1c0 = (float*)(rstats + 131072);           // 1,024 f32
  float* Spart = c1c0 + 1024;                        // 32,768 f32
  float* Upart = Spart + 32768;                      // 8,388,608 f32
  float* outS = (float*)d_out;
  float* outA = outS + 65536;

  k0<<<3392, 256, 0, stream>>>(Wk, Wv, Wih, Whh, W1, W2, Wq, lnig, lnib,
                               Wgb, Wihb, Whhb, W1b, W2b, Wqb, c1c0,
                               noise, mu, ls, lnsg, lnsb, slots, qbuf,
                               emb, rstats);
  k1b<<<4096, 256, 0, stream>>>(emb, Wgb, rstats, c1c0, keys, vpan);
  for (int it=0; it<3; ++it){
    int lastf = (it==2) ? 1 : 0;
    k3<<<4096, 256, 0, stream>>>(keys, vpan, qbuf, Upart, Spart, outA, lastf);
    k4<<<256, 256, 0, stream>>>(Upart, Spart, slots, bih, bhh, Wihb, Whhb, W1b, W2b, Wqb,
                                b1, b2, lnfg, lnfb, lnsg, lnsb, qbuf, outS, lastf);
  }
}